// Round 1
// 228.604 us; speedup vs baseline: 1.0134x; 1.0134x over previous
//
#include <hip/hip_runtime.h>
#include <hip/hip_fp16.h>

typedef _Float16 v8h __attribute__((ext_vector_type(8)));
typedef _Float16 v4h __attribute__((ext_vector_type(4)));
typedef _Float16 v2h __attribute__((ext_vector_type(2)));
typedef float v4f __attribute__((ext_vector_type(4)));

#define MFMA_F16 __builtin_amdgcn_mfma_f32_16x16x32_f16
#define EXP2F __builtin_amdgcn_exp2f

__device__ static inline v2h pkrtz(float a, float b) {
  return __builtin_bit_cast(v2h, __builtin_amdgcn_cvt_pkrtz(a, b));
}

__device__ static inline void async_copy16(const void* g, void* l) {
  __builtin_amdgcn_global_load_lds(
      (const __attribute__((address_space(1))) void*)g,
      (__attribute__((address_space(3))) void*)l, 16, 0, 0);
}

// ---------------- flattened batched cast fp32 -> f16 (x8) -------------------
struct CastArgs {
  const float* src[10];
  _Float16* dst[10];
  int start[11];   // prefix offsets in v8-chunks; start[10] = total
  float scale[10];
};
__global__ void cast_all(CastArgs a) {
  const int g = blockIdx.x * 256 + threadIdx.x;
  if (g >= a.start[10]) return;
  int z = 0;
  #pragma unroll
  for (int i = 1; i < 10; ++i) if (g >= a.start[i]) z = i;
  const int i0 = g - a.start[z];
  const float sc = a.scale[z];
  const float* s = a.src[z] + (size_t)i0 * 8;
  const float4 f0 = *(const float4*)s;
  const float4 f1 = *(const float4*)(s + 4);
  v8h o = {(_Float16)(f0.x * sc), (_Float16)(f0.y * sc),
           (_Float16)(f0.z * sc), (_Float16)(f0.w * sc),
           (_Float16)(f1.x * sc), (_Float16)(f1.y * sc),
           (_Float16)(f1.z * sc), (_Float16)(f1.w * sc)};
  *(v8h*)(a.dst[z] + (size_t)i0 * 8) = o;
}

// ---------------- batched f16 GEMM: out_z = A_z @ W_z^T + bias --------------
// MT = M-tile (128 or 64). N-tile 128, BK=64, async staging, XOR-swizzled.
// mode: 0 = f16 row-major, 1 = f16 V-transpose [bh][dk][s'] (PV-permuted),
//       2 = f32 row-major.
struct GemmArgs {
  const _Float16* A1[4]; const _Float16* A2[4];
  const _Float16* W1[4]; const _Float16* W2[4];
  const float* b1[4];    const float* b2[4];
  void* out[4];
  float bscale[4];
  int K[4];
  int mode[4];
};

template <int MT>
__global__ __launch_bounds__(256) void gemm_mt(GemmArgs g) {
  constexpr int iA = MT / 32;          // A staging instructions per thread
  constexpr int NMT = MT / 32;         // m-subtiles per wave
  __shared__ _Float16 a_lds[MT * 64];
  __shared__ _Float16 w_lds[128 * 64];
  const int z = blockIdx.z;
  const int KK = g.K[z];
  const int tid = threadIdx.x;
  const int w = tid >> 6, lane = tid & 63, quad = lane >> 4, l16 = lane & 15;
  const int m0 = blockIdx.x * MT, n0 = blockIdx.y * 128;
  const int wm = (w >> 1) * (MT / 2), wn = (w & 1) * 64;

  size_t srcOff[4]; int ldsOff[4];
  #pragma unroll
  for (int i = 0; i < 4; ++i) {
    const int c = i * 256 + tid, row = c >> 3, slot = c & 7;
    srcOff[i] = (size_t)row * 768 + (size_t)((slot ^ (row & 7)) * 8);
    ldsOff[i] = (i * 256 + w * 64) * 8;
  }

  v4f acc[NMT][4] = {};

  for (int k0 = 0; k0 < KK; k0 += 64) {
    const _Float16* Asrc = (k0 < 768) ? g.A1[z] : g.A2[z];
    const _Float16* Wsrc = (k0 < 768) ? g.W1[z] : g.W2[z];
    const int kc = (k0 < 768) ? k0 : k0 - 768;
    __syncthreads();
    #pragma unroll
    for (int i = 0; i < 4; ++i) {
      if (i < iA)
        async_copy16(Asrc + (size_t)m0 * 768 + kc + srcOff[i], &a_lds[ldsOff[i]]);
      async_copy16(Wsrc + (size_t)n0 * 768 + kc + srcOff[i], &w_lds[ldsOff[i]]);
    }
    __syncthreads();

    #pragma unroll
    for (int kh = 0; kh < 2; ++kh) {
      v8h af[NMT], bf[4];
      #pragma unroll
      for (int mt = 0; mt < NMT; ++mt) {
        const int r = wm + mt * 16 + l16;
        af[mt] = *(const v8h*)&a_lds[r * 64 + (((kh * 4 + quad) ^ (r & 7)) * 8)];
      }
      #pragma unroll
      for (int nt = 0; nt < 4; ++nt) {
        const int r = wn + nt * 16 + l16;
        bf[nt] = *(const v8h*)&w_lds[r * 64 + (((kh * 4 + quad) ^ (r & 7)) * 8)];
      }
      #pragma unroll
      for (int mt = 0; mt < NMT; ++mt)
        #pragma unroll
        for (int nt = 0; nt < 4; ++nt)
          acc[mt][nt] = MFMA_F16(af[mt], bf[nt], acc[mt][nt], 0, 0, 0);
    }
  }

  const int mode = g.mode[z];
  #pragma unroll
  for (int nt = 0; nt < 4; ++nt) {
    const int col = n0 + wn + nt * 16 + l16;
    float bv = g.b1[z][col] * g.bscale[z];
    if (g.b2[z]) bv += g.b2[z][col];
    if (mode == 1) {
      // Vt[((b*12+h)*64+dk)*1024 + s'];  s = tile|q4|j -> s' = q4|tile|j
      _Float16* outp = (_Float16*)g.out[z];
      const int h = col >> 6, dk = col & 63;
      #pragma unroll
      for (int mt = 0; mt < NMT; ++mt) {
        const int row = m0 + wm + mt * 16 + quad * 4;
        const int b = row >> 10, s = row & 1023;
        const int sp = (s & ~31) | ((s & 12) << 1) | ((s & 16) >> 2);
        v4h pack = {(_Float16)(acc[mt][nt][0] + bv), (_Float16)(acc[mt][nt][1] + bv),
                    (_Float16)(acc[mt][nt][2] + bv), (_Float16)(acc[mt][nt][3] + bv)};
        *(v4h*)&outp[(size_t)((b * 12 + h) * 64 + dk) * 1024 + sp] = pack;
      }
    } else {
      #pragma unroll
      for (int mt = 0; mt < NMT; ++mt)
        #pragma unroll
        for (int r = 0; r < 4; ++r) {
          const int row = m0 + wm + mt * 16 + quad * 4 + r;
          const float v = acc[mt][nt][r] + bv;
          if (mode == 2) ((float*)g.out[z])[(size_t)row * 768 + col] = v;
          else ((_Float16*)g.out[z])[(size_t)row * 768 + col] = (_Float16)v;
        }
    }
  }
}

// ---------------- fused dual-time attention (transposed-score, all-x32) ----
// grid (S/64, B*H); block 256 (4 waves, 16 q each). 64-kv chunks, dbuf.
// Changes this round:
//  * bijective XCD swizzle: the 16 q-tiles of each bh colocate on one XCD
//    (6 bh/XCD -> 2.25 MB KV working set, L2-resident; fetch ~77->~26 MB)
//  * unified LDS array + 8 hoisted row addresses; all 24 ds_read_b128 per
//    chunk are VGPR-addr + compile-time immediate (kills per-chunk addr VALU)
//  * incremental staging pointers (3 ptr adds/chunk instead of 6 mul+add64)
//  * s_setprio(1) around the two MFMA clusters (T5, attn-proven)
__global__ __launch_bounds__(256) void attn(
    const _Float16* __restrict__ Q,
    const _Float16* __restrict__ KT0, const _Float16* __restrict__ KT1,
    const _Float16* __restrict__ Vt,   // [48*64][1024] permuted
    _Float16* __restrict__ X)          // [B*S,768]
{
  // byte offsets inside lds: KT0: buf*8192 | KT1: 16384+buf*8192 | VT: 32768+buf*8192
  __shared__ _Float16 lds[6 * 4096];

  const int tid = threadIdx.x;
  const int w = tid >> 6, lane = tid & 63, quad = lane >> 4, l16 = lane & 15;

  // XCD-aware bijective swizzle (gridDim = (16,48), 768 = 8 XCD * 96)
  const int orig = blockIdx.y * 16 + blockIdx.x;
  const int wgid = (orig & 7) * 96 + (orig >> 3);
  const int bh = wgid >> 4, q0 = (wgid & 15) * 64;
  const int b = bh / 12, h = bh % 12;
  const size_t base = (size_t)b * 1024 * 768 + h * 64;

  const _Float16* k0s = KT0 + base;
  const _Float16* k1s = KT1 + base;
  const _Float16* vs  = Vt + (size_t)bh * 64 * 1024;

  size_t ktOff[2], vOff[2]; int ldsOff[2];
  #pragma unroll
  for (int i = 0; i < 2; ++i) {
    const int c = i * 256 + w * 64 + lane, row = c >> 3, slot = c & 7;
    const int logical = slot ^ (row & 7);
    ktOff[i] = (size_t)row * 768 + (size_t)(logical * 8);
    vOff[i] = (size_t)row * 1024 + (size_t)(logical * 8);
    ldsOff[i] = c * 8;
  }
  auto stage = [&](int buf) {
    #pragma unroll
    for (int i = 0; i < 2; ++i) {
      async_copy16(k0s + ktOff[i], &lds[buf * 4096 + ldsOff[i]]);
      async_copy16(k1s + ktOff[i], &lds[8192 + buf * 4096 + ldsOff[i]]);
      async_copy16(vs + vOff[i], &lds[16384 + buf * 4096 + ldsOff[i]]);
    }
    k0s += 64 * 768; k1s += 64 * 768; vs += 64;
  };

  const _Float16* Qw = Q + base + (size_t)(q0 + w * 16) * 768;
  const v8h qf0 = *(const v8h*)(Qw + (size_t)l16 * 768 + quad * 8);
  const v8h qf1 = *(const v8h*)(Qw + (size_t)l16 * 768 + 32 + quad * 8);

  // Hoisted LDS row addresses (bytes). KT rows (kvt) and V rows (dkt) share
  // the same {row, slot} address pairs; slot pair differs by XOR 64 bytes.
  int ra0[4], ra1[4];
  #pragma unroll
  for (int t = 0; t < 4; ++t) {
    const int r = t * 16 + l16, rw = r & 7;
    ra0[t] = (r * 64 + ((quad ^ rw) * 8)) * 2;
    ra1[t] = ra0[t] ^ 64;
  }

  const _Float16 one = (_Float16)1.f;
  const v8h ones8 = {one, one, one, one, one, one, one, one};
  v4f o[2][4] = {};      // O^T tiles [t][dkt]
  v4f osum[2] = {};      // softmax denominators

  auto body = [&](int B, bool doStage) {   // B = buf * 8192 (byte offset)
    __syncthreads();
    if (doStage) stage((B == 0) ? 1 : 0);

    const char* L = (const char*)lds;

    // S^T tiles [t][kvt]: A = KT frag (m=kv), B = Q frag
    v4f s[2][4];
    __builtin_amdgcn_s_setprio(1);
    #pragma unroll
    for (int kvt = 0; kvt < 4; ++kvt) {
      const v8h k00 = *(const v8h*)(L + B + ra0[kvt]);
      const v8h k01 = *(const v8h*)(L + B + ra1[kvt]);
      const v8h k10 = *(const v8h*)(L + 16384 + B + ra0[kvt]);
      const v8h k11 = *(const v8h*)(L + 16384 + B + ra1[kvt]);
      s[0][kvt] = MFMA_F16(k00, qf0, v4f{}, 0, 0, 0);
      s[0][kvt] = MFMA_F16(k01, qf1, s[0][kvt], 0, 0, 0);
      s[1][kvt] = MFMA_F16(k10, qf0, v4f{}, 0, 0, 0);
      s[1][kvt] = MFMA_F16(k11, qf1, s[1][kvt], 0, 0, 0);
    }
    __builtin_amdgcn_s_setprio(0);

    // P = exp2(s), packed (rtz) into x32 B-frags: pb8[t][g] = {tile g*2, g*2+1}
    v8h pb8[2][2];
    #pragma unroll
    for (int t = 0; t < 2; ++t)
      #pragma unroll
      for (int gg = 0; gg < 2; ++gg) {
        const v4f sa = s[t][gg * 2], sb = s[t][gg * 2 + 1];
        const v2h a0 = pkrtz(EXP2F(sa[0]), EXP2F(sa[1]));
        const v2h a1 = pkrtz(EXP2F(sa[2]), EXP2F(sa[3]));
        const v2h b0 = pkrtz(EXP2F(sb[0]), EXP2F(sb[1]));
        const v2h b1 = pkrtz(EXP2F(sb[2]), EXP2F(sb[3]));
        pb8[t][gg] = v8h{a0[0], a0[1], a1[0], a1[1], b0[0], b0[1], b1[0], b1[1]};
        osum[t] = MFMA_F16(ones8, pb8[t][gg], osum[t], 0, 0, 0);
      }

    // PV (x32): A = V^T b128 (permuted layout matches pb8's k-mapping)
    __builtin_amdgcn_s_setprio(1);
    #pragma unroll
    for (int dkt = 0; dkt < 4; ++dkt) {
      const v8h v0 = *(const v8h*)(L + 32768 + B + ra0[dkt]);
      const v8h v1 = *(const v8h*)(L + 32768 + B + ra1[dkt]);
      o[0][dkt] = MFMA_F16(v0, pb8[0][0], o[0][dkt], 0, 0, 0);
      o[0][dkt] = MFMA_F16(v1, pb8[0][1], o[0][dkt], 0, 0, 0);
      o[1][dkt] = MFMA_F16(v0, pb8[1][0], o[1][dkt], 0, 0, 0);
      o[1][dkt] = MFMA_F16(v1, pb8[1][1], o[1][dkt], 0, 0, 0);
    }
    __builtin_amdgcn_s_setprio(0);
  };

  stage(0);
  for (int it = 0; it < 7; ++it) {
    body(0, true);
    body(8192, true);
  }
  body(0, true);
  body(8192, false);

  const float i0 = 1.0f / osum[0][0], i1 = 1.0f / osum[1][0];

  _Float16* Xw = X + base + (size_t)(q0 + w * 16 + l16) * 768;
  #pragma unroll
  for (int dkt = 0; dkt < 4; ++dkt) {
    v4h pack;
    #pragma unroll
    for (int r = 0; r < 4; ++r)
      pack[r] = (_Float16)(o[0][dkt][r] * i0 + o[1][dkt][r] * i1);
    *(v4h*)&Xw[dkt * 16 + quad * 4] = pack;
  }
}

extern "C" void kernel_launch(void* const* d_in, const int* in_sizes, int n_in,
                              void* d_out, int out_size, void* d_ws, size_t ws_size,
                              hipStream_t stream) {
  const float* query = (const float*)d_in[0];
  const float* key   = (const float*)d_in[1];
  const float* value = (const float*)d_in[2];
  const float* times = (const float*)d_in[3];
  const float* Wq = (const float*)d_in[4];  const float* bq = (const float*)d_in[5];
  const float* Wk = (const float*)d_in[6];  const float* bk = (const float*)d_in[7];
  const float* Wv = (const float*)d_in[8];  const float* bv = (const float*)d_in[9];
  const float* Wt = (const float*)d_in[10]; const float* bt = (const float*)d_in[11];
  const float* Wo = (const float*)d_in[12]; const float* bo = (const float*)d_in[13];
  float* out = (float*)d_out;

  const size_t NELEM = (size_t)4096 * 768;
  const size_t WELEM = (size_t)768 * 768;
  const float QSCALE = 0.125f * 1.4426950408889634f;  // 1/sqrt(64)*log2(e)

  char* ws = (char*)d_ws;
  size_t off = 0;
  auto alloc = [&](size_t bytes) {
    void* p = ws + off; off += (bytes + 255) & ~(size_t)255; return p;
  };
  _Float16* qh  = (_Float16*)alloc(NELEM * 2);  // casted query; later Xh
  _Float16* kh  = (_Float16*)alloc(NELEM * 2);
  _Float16* vh  = (_Float16*)alloc(NELEM * 2);
  _Float16* wqh = (_Float16*)alloc(WELEM * 2);
  _Float16* wkh = (_Float16*)alloc(WELEM * 2);
  _Float16* wvh = (_Float16*)alloc(WELEM * 2);
  _Float16* wth = (_Float16*)alloc(WELEM * 2);
  _Float16* woh = (_Float16*)alloc(WELEM * 2);
  _Float16* Qh  = (_Float16*)alloc(NELEM * 2);
  _Float16* KT0 = (_Float16*)alloc(NELEM * 2);
  _Float16* KT1 = (_Float16*)alloc(NELEM * 2);
  _Float16* Vt  = (_Float16*)alloc(NELEM * 2);
  _Float16* t0h = (_Float16*)d_out;      // dead before final fp32 write
  _Float16* t1h = t0h + NELEM;
  _Float16* Xh = qh;                     // overlay: query dead after proj

  // ---- 1. flattened batched cast ----
  CastArgs ca = {};
  const int nA8 = (int)(NELEM / 8), nW8 = (int)(WELEM / 8);
  const float* csrc[10] = {query, key, value, times, times + NELEM, Wq, Wk, Wv, Wt, Wo};
  _Float16* cdst[10] = {qh, kh, vh, t0h, t1h, wqh, wkh, wvh, wth, woh};
  int acc8 = 0;
  for (int i = 0; i < 10; ++i) {
    ca.src[i] = csrc[i]; ca.dst[i] = cdst[i];
    ca.start[i] = acc8;
    acc8 += (i < 5) ? nA8 : nW8;
    ca.scale[i] = (i == 5) ? QSCALE : 1.0f;
  }
  ca.start[10] = acc8;
  cast_all<<<dim3((acc8 + 255) / 256), 256, 0, stream>>>(ca);

  // ---- 2. batched projections: z = {KT0, KT1, Q, V} ----
  GemmArgs pa = {};
  pa.A1[0] = t0h; pa.A2[0] = kh; pa.W1[0] = wth; pa.W2[0] = wkh;
  pa.b1[0] = bt; pa.b2[0] = bk; pa.out[0] = KT0; pa.bscale[0] = 1.0f;
  pa.K[0] = 1536; pa.mode[0] = 0;
  pa.A1[1] = t1h; pa.A2[1] = kh; pa.W1[1] = wth; pa.W2[1] = wkh;
  pa.b1[1] = bt; pa.b2[1] = bk; pa.out[1] = KT1; pa.bscale[1] = 1.0f;
  pa.K[1] = 1536; pa.mode[1] = 0;
  pa.A1[2] = qh; pa.A2[2] = qh; pa.W1[2] = wqh; pa.W2[2] = wqh;
  pa.b1[2] = bq; pa.b2[2] = nullptr; pa.out[2] = Qh; pa.bscale[2] = QSCALE;
  pa.K[2] = 768; pa.mode[2] = 0;
  pa.A1[3] = vh; pa.A2[3] = vh; pa.W1[3] = wvh; pa.W2[3] = wvh;
  pa.b1[3] = bv; pa.b2[3] = nullptr; pa.out[3] = Vt; pa.bscale[3] = 1.0f;
  pa.K[3] = 768; pa.mode[3] = 1;
  gemm_mt<128><<<dim3(32, 6, 4), 256, 0, stream>>>(pa);

  // ---- 3. fused dual-time attention -> Xh ----
  attn<<<dim3(16, 48), 256, 0, stream>>>(Qh, KT0, KT1, Vt, Xh);

  // ---- 4. output projection -> d_out (fp32), 64-row tiles for 384 blocks ----
  GemmArgs oa = {};
  oa.A1[0] = Xh; oa.A2[0] = Xh; oa.W1[0] = woh; oa.W2[0] = woh;
  oa.b1[0] = bo; oa.b2[0] = nullptr; oa.out[0] = out; oa.bscale[0] = 1.0f;
  oa.K[0] = 768; oa.mode[0] = 2;
  gemm_mt<64><<<dim3(64, 6, 1), 256, 0, stream>>>(oa);
}

// Round 2
// 218.582 us; speedup vs baseline: 1.0598x; 1.0458x over previous
//
#include <hip/hip_runtime.h>
#include <hip/hip_fp16.h>

typedef _Float16 v8h __attribute__((ext_vector_type(8)));
typedef _Float16 v4h __attribute__((ext_vector_type(4)));
typedef _Float16 v2h __attribute__((ext_vector_type(2)));
typedef float v4f __attribute__((ext_vector_type(4)));

#define MFMA_F16 __builtin_amdgcn_mfma_f32_16x16x32_f16
#define EXP2F __builtin_amdgcn_exp2f

__device__ static inline v2h pkrtz(float a, float b) {
  return __builtin_bit_cast(v2h, __builtin_amdgcn_cvt_pkrtz(a, b));
}

__device__ static inline void async_copy16(const void* g, void* l) {
  __builtin_amdgcn_global_load_lds(
      (const __attribute__((address_space(1))) void*)g,
      (__attribute__((address_space(3))) void*)l, 16, 0, 0);
}

// ---------------- batched cast fp32 -> f16 (weights only now) ---------------
struct CastArgs {
  const float* src[5];
  _Float16* dst[5];
  int start[6];   // prefix offsets in v8-chunks; start[5] = total
  float scale[5];
};
__global__ void cast_all(CastArgs a) {
  const int g = blockIdx.x * 256 + threadIdx.x;
  if (g >= a.start[5]) return;
  int z = 0;
  #pragma unroll
  for (int i = 1; i < 5; ++i) if (g >= a.start[i]) z = i;
  const int i0 = g - a.start[z];
  const float sc = a.scale[z];
  const float* s = a.src[z] + (size_t)i0 * 8;
  const float4 f0 = *(const float4*)s;
  const float4 f1 = *(const float4*)(s + 4);
  v8h o = {(_Float16)(f0.x * sc), (_Float16)(f0.y * sc),
           (_Float16)(f0.z * sc), (_Float16)(f0.w * sc),
           (_Float16)(f1.x * sc), (_Float16)(f1.y * sc),
           (_Float16)(f1.z * sc), (_Float16)(f1.w * sc)};
  *(v8h*)(a.dst[z] + (size_t)i0 * 8) = o;
}

// ---------------- batched GEMM: out_z = A_z @ W_z^T + bias ------------------
// MT = M-tile. N-tile 128, BK=64, XOR-swizzled LDS.
// AF32: A is fp32 in HBM; reg-staged (dwordx4 -> cvt f16 -> swizzled
//       ds_write_b128), loads for k+1 issued after the compute-entry barrier
//       so HBM latency hides under MFMA (T14). W double-buffered via
//       global_load_lds, also issued post-barrier (T3-minimum pipeline) —
//       per-k-step exposed stall is only the ds_write lgkm drain.
// !AF32: A is f16, staged via global_load_lds, A+W double-buffered, single
//        barrier per k-step.
// mode: 0 = f16 row-major, 1 = f16 V-transpose [bh][dk][s'] (PV-permuted),
//       2 = f32 row-major.
struct GemmArgs {
  const void* A1[4]; const void* A2[4];
  const _Float16* W1[4]; const _Float16* W2[4];
  const float* b1[4];    const float* b2[4];
  void* out[4];
  float bscale[4];
  int K[4];
  int mode[4];
};

template <int MT, bool AF32>
__global__ __launch_bounds__(256) void gemm_mt(GemmArgs g) {
  constexpr int NMT = MT / 32;          // m-subtiles per wave
  constexpr int ASLOT = MT / 32;        // v8h LDS slots per thread for A
  __shared__ _Float16 a_lds[(AF32 ? 1 : 2) * MT * 64];
  __shared__ _Float16 w_lds[2 * 128 * 64];
  const int z = blockIdx.z;
  const int KK = g.K[z];
  const int tid = threadIdx.x;
  const int w = tid >> 6, lane = tid & 63, quad = lane >> 4, l16 = lane & 15;
  const int m0 = blockIdx.x * MT, n0 = blockIdx.y * 128;
  const int wm = (w >> 1) * (MT / 2), wn = (w & 1) * 64;

  // global_load_lds chunk offsets (shared by W always, and A when !AF32)
  size_t srcOffW[4]; int ldsOffW[4];
  #pragma unroll
  for (int i = 0; i < 4; ++i) {
    const int c = i * 256 + tid, row = c >> 3, slot = c & 7;
    srcOffW[i] = (size_t)row * 768 + (size_t)((slot ^ (row & 7)) * 8);
    ldsOffW[i] = (i * 256 + w * 64) * 8;
  }

  auto stageW = [&](const _Float16* Wsrc, int kc, int buf) {
    #pragma unroll
    for (int i = 0; i < 4; ++i)
      async_copy16(Wsrc + (size_t)n0 * 768 + kc + srcOffW[i],
                   &w_lds[buf * 8192 + ldsOffW[i]]);
  };
  auto stageA16 = [&](const _Float16* Asrc, int kc, int buf) {
    #pragma unroll
    for (int i = 0; i < MT / 32; ++i)
      async_copy16(Asrc + (size_t)m0 * 768 + kc + srcOffW[i],
                   &a_lds[buf * MT * 64 + ldsOffW[i]]);
  };

  // reg-staged fp32 A path
  int rowA[ASLOT], colA[ASLOT], dstA[ASLOT];
  float4 areg[ASLOT][2];
  if constexpr (AF32) {
    #pragma unroll
    for (int i = 0; i < ASLOT; ++i) {
      const int s = i * 256 + tid, row = s >> 3, slot = s & 7;
      rowA[i] = row;
      colA[i] = (slot ^ (row & 7)) * 8;
      dstA[i] = s * 8;
    }
  }
  auto loadA = [&](const float* Af, int kc) {
    #pragma unroll
    for (int i = 0; i < ASLOT; ++i) {
      const float* p = Af + (size_t)(m0 + rowA[i]) * 768 + kc + colA[i];
      areg[i][0] = *(const float4*)p;
      areg[i][1] = *(const float4*)(p + 4);
    }
  };
  auto writeA = [&]() {
    #pragma unroll
    for (int i = 0; i < ASLOT; ++i) {
      const float4 f0 = areg[i][0], f1 = areg[i][1];
      v8h o = {(_Float16)f0.x, (_Float16)f0.y, (_Float16)f0.z, (_Float16)f0.w,
               (_Float16)f1.x, (_Float16)f1.y, (_Float16)f1.z, (_Float16)f1.w};
      *(v8h*)&a_lds[dstA[i]] = o;
    }
  };

  const void* A1 = g.A1[z]; const void* A2 = g.A2[z];
  const _Float16* W1 = g.W1[z]; const _Float16* W2 = g.W2[z];

  v4f acc[NMT][4] = {};

  // prologue: stage k=0 into buf 0
  if constexpr (AF32) loadA((const float*)A1, 0);
  else stageA16((const _Float16*)A1, 0, 0);
  stageW(W1, 0, 0);

  int cur = 0;
  for (int k0 = 0; k0 < KK; k0 += 64) {
    const int k0n = k0 + 64;
    const bool has_next = k0n < KK;
    const int kcn = (k0n < 768) ? k0n : k0n - 768;
    const bool nfirst = k0n < 768;

    __syncthreads();   // drains k0's staging (vmcnt for copies/loads)

    if constexpr (AF32) {
      writeA();        // regs -> swizzled a_lds
      __syncthreads(); // lgkm drain; a_lds visible to all waves
      if (has_next) {
        loadA((const float*)(nfirst ? A1 : A2), kcn);   // hides under MFMA
        stageW(nfirst ? W1 : W2, kcn, cur ^ 1);
      }
    } else {
      if (has_next) {
        stageA16((const _Float16*)(nfirst ? A1 : A2), kcn, cur ^ 1);
        stageW(nfirst ? W1 : W2, kcn, cur ^ 1);
      }
    }

    const _Float16* al;
    if constexpr (AF32) al = a_lds; else al = &a_lds[cur * MT * 64];
    const _Float16* wl = &w_lds[cur * 8192];

    #pragma unroll
    for (int kh = 0; kh < 2; ++kh) {
      v8h af[NMT], bf[4];
      #pragma unroll
      for (int mt = 0; mt < NMT; ++mt) {
        const int r = wm + mt * 16 + l16;
        af[mt] = *(const v8h*)&al[r * 64 + (((kh * 4 + quad) ^ (r & 7)) * 8)];
      }
      #pragma unroll
      for (int nt = 0; nt < 4; ++nt) {
        const int r = wn + nt * 16 + l16;
        bf[nt] = *(const v8h*)&wl[r * 64 + (((kh * 4 + quad) ^ (r & 7)) * 8)];
      }
      #pragma unroll
      for (int mt = 0; mt < NMT; ++mt)
        #pragma unroll
        for (int nt = 0; nt < 4; ++nt)
          acc[mt][nt] = MFMA_F16(af[mt], bf[nt], acc[mt][nt], 0, 0, 0);
    }
    cur ^= 1;
  }

  const int mode = g.mode[z];
  #pragma unroll
  for (int nt = 0; nt < 4; ++nt) {
    const int col = n0 + wn + nt * 16 + l16;
    float bv = g.b1[z][col] * g.bscale[z];
    if (g.b2[z]) bv += g.b2[z][col];
    if (mode == 1) {
      // Vt[((b*12+h)*64+dk)*1024 + s'];  s = tile|q4|j -> s' = q4|tile|j
      _Float16* outp = (_Float16*)g.out[z];
      const int h = col >> 6, dk = col & 63;
      #pragma unroll
      for (int mt = 0; mt < NMT; ++mt) {
        const int row = m0 + wm + mt * 16 + quad * 4;
        const int b = row >> 10, s = row & 1023;
        const int sp = (s & ~31) | ((s & 12) << 1) | ((s & 16) >> 2);
        v4h pack = {(_Float16)(acc[mt][nt][0] + bv), (_Float16)(acc[mt][nt][1] + bv),
                    (_Float16)(acc[mt][nt][2] + bv), (_Float16)(acc[mt][nt][3] + bv)};
        *(v4h*)&outp[(size_t)((b * 12 + h) * 64 + dk) * 1024 + sp] = pack;
      }
    } else {
      #pragma unroll
      for (int mt = 0; mt < NMT; ++mt)
        #pragma unroll
        for (int r = 0; r < 4; ++r) {
          const int row = m0 + wm + mt * 16 + quad * 4 + r;
          const float v = acc[mt][nt][r] + bv;
          if (mode == 2) ((float*)g.out[z])[(size_t)row * 768 + col] = v;
          else ((_Float16*)g.out[z])[(size_t)row * 768 + col] = (_Float16)v;
        }
    }
  }
}

// ---------------- fused dual-time attention (transposed-score, all-x32) ----
// grid (S/64, B*H); block 256 (4 waves, 16 q each). 64-kv chunks, dbuf.
// Unchanged from round 1 (verified): XCD-bijective swizzle, unified LDS,
// hoisted row addresses, incremental staging pointers, setprio around MFMA.
__global__ __launch_bounds__(256) void attn(
    const _Float16* __restrict__ Q,
    const _Float16* __restrict__ KT0, const _Float16* __restrict__ KT1,
    const _Float16* __restrict__ Vt,   // [48*64][1024] permuted
    _Float16* __restrict__ X)          // [B*S,768]
{
  __shared__ _Float16 lds[6 * 4096];

  const int tid = threadIdx.x;
  const int w = tid >> 6, lane = tid & 63, quad = lane >> 4, l16 = lane & 15;

  const int orig = blockIdx.y * 16 + blockIdx.x;
  const int wgid = (orig & 7) * 96 + (orig >> 3);
  const int bh = wgid >> 4, q0 = (wgid & 15) * 64;
  const int b = bh / 12, h = bh % 12;
  const size_t base = (size_t)b * 1024 * 768 + h * 64;

  const _Float16* k0s = KT0 + base;
  const _Float16* k1s = KT1 + base;
  const _Float16* vs  = Vt + (size_t)bh * 64 * 1024;

  size_t ktOff[2], vOff[2]; int ldsOff[2];
  #pragma unroll
  for (int i = 0; i < 2; ++i) {
    const int c = i * 256 + w * 64 + lane, row = c >> 3, slot = c & 7;
    const int logical = slot ^ (row & 7);
    ktOff[i] = (size_t)row * 768 + (size_t)(logical * 8);
    vOff[i] = (size_t)row * 1024 + (size_t)(logical * 8);
    ldsOff[i] = c * 8;
  }
  auto stage = [&](int buf) {
    #pragma unroll
    for (int i = 0; i < 2; ++i) {
      async_copy16(k0s + ktOff[i], &lds[buf * 4096 + ldsOff[i]]);
      async_copy16(k1s + ktOff[i], &lds[8192 + buf * 4096 + ldsOff[i]]);
      async_copy16(vs + vOff[i], &lds[16384 + buf * 4096 + ldsOff[i]]);
    }
    k0s += 64 * 768; k1s += 64 * 768; vs += 64;
  };

  const _Float16* Qw = Q + base + (size_t)(q0 + w * 16) * 768;
  const v8h qf0 = *(const v8h*)(Qw + (size_t)l16 * 768 + quad * 8);
  const v8h qf1 = *(const v8h*)(Qw + (size_t)l16 * 768 + 32 + quad * 8);

  int ra0[4], ra1[4];
  #pragma unroll
  for (int t = 0; t < 4; ++t) {
    const int r = t * 16 + l16, rw = r & 7;
    ra0[t] = (r * 64 + ((quad ^ rw) * 8)) * 2;
    ra1[t] = ra0[t] ^ 64;
  }

  const _Float16 one = (_Float16)1.f;
  const v8h ones8 = {one, one, one, one, one, one, one, one};
  v4f o[2][4] = {};      // O^T tiles [t][dkt]
  v4f osum[2] = {};      // softmax denominators

  auto body = [&](int B, bool doStage) {   // B = buf * 8192 (byte offset)
    __syncthreads();
    if (doStage) stage((B == 0) ? 1 : 0);

    const char* L = (const char*)lds;

    v4f s[2][4];
    __builtin_amdgcn_s_setprio(1);
    #pragma unroll
    for (int kvt = 0; kvt < 4; ++kvt) {
      const v8h k00 = *(const v8h*)(L + B + ra0[kvt]);
      const v8h k01 = *(const v8h*)(L + B + ra1[kvt]);
      const v8h k10 = *(const v8h*)(L + 16384 + B + ra0[kvt]);
      const v8h k11 = *(const v8h*)(L + 16384 + B + ra1[kvt]);
      s[0][kvt] = MFMA_F16(k00, qf0, v4f{}, 0, 0, 0);
      s[0][kvt] = MFMA_F16(k01, qf1, s[0][kvt], 0, 0, 0);
      s[1][kvt] = MFMA_F16(k10, qf0, v4f{}, 0, 0, 0);
      s[1][kvt] = MFMA_F16(k11, qf1, s[1][kvt], 0, 0, 0);
    }
    __builtin_amdgcn_s_setprio(0);

    v8h pb8[2][2];
    #pragma unroll
    for (int t = 0; t < 2; ++t)
      #pragma unroll
      for (int gg = 0; gg < 2; ++gg) {
        const v4f sa = s[t][gg * 2], sb = s[t][gg * 2 + 1];
        const v2h a0 = pkrtz(EXP2F(sa[0]), EXP2F(sa[1]));
        const v2h a1 = pkrtz(EXP2F(sa[2]), EXP2F(sa[3]));
        const v2h b0 = pkrtz(EXP2F(sb[0]), EXP2F(sb[1]));
        const v2h b1 = pkrtz(EXP2F(sb[2]), EXP2F(sb[3]));
        pb8[t][gg] = v8h{a0[0], a0[1], a1[0], a1[1], b0[0], b0[1], b1[0], b1[1]};
        osum[t] = MFMA_F16(ones8, pb8[t][gg], osum[t], 0, 0, 0);
      }

    __builtin_amdgcn_s_setprio(1);
    #pragma unroll
    for (int dkt = 0; dkt < 4; ++dkt) {
      const v8h v0 = *(const v8h*)(L + 32768 + B + ra0[dkt]);
      const v8h v1 = *(const v8h*)(L + 32768 + B + ra1[dkt]);
      o[0][dkt] = MFMA_F16(v0, pb8[0][0], o[0][dkt], 0, 0, 0);
      o[0][dkt] = MFMA_F16(v1, pb8[0][1], o[0][dkt], 0, 0, 0);
      o[1][dkt] = MFMA_F16(v0, pb8[1][0], o[1][dkt], 0, 0, 0);
      o[1][dkt] = MFMA_F16(v1, pb8[1][1], o[1][dkt], 0, 0, 0);
    }
    __builtin_amdgcn_s_setprio(0);
  };

  stage(0);
  for (int it = 0; it < 7; ++it) {
    body(0, true);
    body(8192, true);
  }
  body(0, true);
  body(8192, false);

  const float i0 = 1.0f / osum[0][0], i1 = 1.0f / osum[1][0];

  _Float16* Xw = X + base + (size_t)(q0 + w * 16 + l16) * 768;
  #pragma unroll
  for (int dkt = 0; dkt < 4; ++dkt) {
    v4h pack;
    #pragma unroll
    for (int r = 0; r < 4; ++r)
      pack[r] = (_Float16)(o[0][dkt][r] * i0 + o[1][dkt][r] * i1);
    *(v4h*)&Xw[dkt * 16 + quad * 4] = pack;
  }
}

extern "C" void kernel_launch(void* const* d_in, const int* in_sizes, int n_in,
                              void* d_out, int out_size, void* d_ws, size_t ws_size,
                              hipStream_t stream) {
  const float* query = (const float*)d_in[0];
  const float* key   = (const float*)d_in[1];
  const float* value = (const float*)d_in[2];
  const float* times = (const float*)d_in[3];
  const float* Wq = (const float*)d_in[4];  const float* bq = (const float*)d_in[5];
  const float* Wk = (const float*)d_in[6];  const float* bk = (const float*)d_in[7];
  const float* Wv = (const float*)d_in[8];  const float* bv = (const float*)d_in[9];
  const float* Wt = (const float*)d_in[10]; const float* bt = (const float*)d_in[11];
  const float* Wo = (const float*)d_in[12]; const float* bo = (const float*)d_in[13];
  float* out = (float*)d_out;

  const size_t NELEM = (size_t)4096 * 768;
  const size_t WELEM = (size_t)768 * 768;
  const float QSCALE = 0.125f * 1.4426950408889634f;  // 1/sqrt(64)*log2(e)

  char* ws = (char*)d_ws;
  size_t off = 0;
  auto alloc = [&](size_t bytes) {
    void* p = ws + off; off += (bytes + 255) & ~(size_t)255; return p;
  };
  _Float16* wqh = (_Float16*)alloc(WELEM * 2);
  _Float16* wkh = (_Float16*)alloc(WELEM * 2);
  _Float16* wvh = (_Float16*)alloc(WELEM * 2);
  _Float16* wth = (_Float16*)alloc(WELEM * 2);
  _Float16* woh = (_Float16*)alloc(WELEM * 2);
  _Float16* Qh  = (_Float16*)alloc(NELEM * 2);
  _Float16* KT0 = (_Float16*)alloc(NELEM * 2);
  _Float16* KT1 = (_Float16*)alloc(NELEM * 2);
  _Float16* Vt  = (_Float16*)alloc(NELEM * 2);
  _Float16* Xh  = (_Float16*)alloc(NELEM * 2);

  // ---- 1. weight cast (A-matrices are consumed fp32 by the GEMM now) ----
  CastArgs ca = {};
  const int nW8 = (int)(WELEM / 8);
  const float* csrc[5] = {Wq, Wk, Wv, Wt, Wo};
  _Float16* cdst[5] = {wqh, wkh, wvh, wth, woh};
  int acc8 = 0;
  for (int i = 0; i < 5; ++i) {
    ca.src[i] = csrc[i]; ca.dst[i] = cdst[i];
    ca.start[i] = acc8;
    acc8 += nW8;
    ca.scale[i] = (i == 0) ? QSCALE : 1.0f;
  }
  ca.start[5] = acc8;
  cast_all<<<dim3((acc8 + 255) / 256), 256, 0, stream>>>(ca);

  // ---- 2. batched projections: z = {KT0, KT1, Q, V}, fp32 A inputs ----
  GemmArgs pa = {};
  pa.A1[0] = times;         pa.A2[0] = key; pa.W1[0] = wth; pa.W2[0] = wkh;
  pa.b1[0] = bt; pa.b2[0] = bk; pa.out[0] = KT0; pa.bscale[0] = 1.0f;
  pa.K[0] = 1536; pa.mode[0] = 0;
  pa.A1[1] = times + NELEM; pa.A2[1] = key; pa.W1[1] = wth; pa.W2[1] = wkh;
  pa.b1[1] = bt; pa.b2[1] = bk; pa.out[1] = KT1; pa.bscale[1] = 1.0f;
  pa.K[1] = 1536; pa.mode[1] = 0;
  pa.A1[2] = query; pa.A2[2] = query; pa.W1[2] = wqh; pa.W2[2] = wqh;
  pa.b1[2] = bq; pa.b2[2] = nullptr; pa.out[2] = Qh; pa.bscale[2] = QSCALE;
  pa.K[2] = 768; pa.mode[2] = 0;
  pa.A1[3] = value; pa.A2[3] = value; pa.W1[3] = wvh; pa.W2[3] = wvh;
  pa.b1[3] = bv; pa.b2[3] = nullptr; pa.out[3] = Vt; pa.bscale[3] = 1.0f;
  pa.K[3] = 768; pa.mode[3] = 1;
  gemm_mt<128, true><<<dim3(32, 6, 4), 256, 0, stream>>>(pa);

  // ---- 3. fused dual-time attention -> Xh ----
  attn<<<dim3(16, 48), 256, 0, stream>>>(Qh, KT0, KT1, Vt, Xh);

  // ---- 4. output projection -> d_out (fp32), f16 A path ----
  GemmArgs oa = {};
  oa.A1[0] = Xh; oa.A2[0] = Xh; oa.W1[0] = woh; oa.W2[0] = woh;
  oa.b1[0] = bo; oa.b2[0] = nullptr; oa.out[0] = out; oa.bscale[0] = 1.0f;
  oa.K[0] = 768; oa.mode[0] = 2;
  gemm_mt<64, false><<<dim3(64, 6, 1), 256, 0, stream>>>(oa);
}

// Round 3
// 215.671 us; speedup vs baseline: 1.0741x; 1.0135x over previous
//
#include <hip/hip_runtime.h>
#include <hip/hip_fp16.h>

typedef _Float16 v8h __attribute__((ext_vector_type(8)));
typedef _Float16 v4h __attribute__((ext_vector_type(4)));
typedef _Float16 v2h __attribute__((ext_vector_type(2)));
typedef float v4f __attribute__((ext_vector_type(4)));

#define MFMA_F16 __builtin_amdgcn_mfma_f32_16x16x32_f16
#define EXP2F __builtin_amdgcn_exp2f
#define SCHED_FENCE() __builtin_amdgcn_sched_barrier(0)

__device__ static inline v2h pkrtz(float a, float b) {
  return __builtin_bit_cast(v2h, __builtin_amdgcn_cvt_pkrtz(a, b));
}

__device__ static inline void async_copy16(const void* g, void* l) {
  __builtin_amdgcn_global_load_lds(
      (const __attribute__((address_space(1))) void*)g,
      (__attribute__((address_space(3))) void*)l, 16, 0, 0);
}

// ---------------- batched cast fp32 -> f16 (weights only) -------------------
struct CastArgs {
  const float* src[5];
  _Float16* dst[5];
  int start[6];   // prefix offsets in v8-chunks; start[5] = total
  float scale[5];
};
__global__ void cast_all(CastArgs a) {
  const int g = blockIdx.x * 256 + threadIdx.x;
  if (g >= a.start[5]) return;
  int z = 0;
  #pragma unroll
  for (int i = 1; i < 5; ++i) if (g >= a.start[i]) z = i;
  const int i0 = g - a.start[z];
  const float sc = a.scale[z];
  const float* s = a.src[z] + (size_t)i0 * 8;
  const float4 f0 = *(const float4*)s;
  const float4 f1 = *(const float4*)(s + 4);
  v8h o = {(_Float16)(f0.x * sc), (_Float16)(f0.y * sc),
           (_Float16)(f0.z * sc), (_Float16)(f0.w * sc),
           (_Float16)(f1.x * sc), (_Float16)(f1.y * sc),
           (_Float16)(f1.z * sc), (_Float16)(f1.w * sc)};
  *(v8h*)(a.dst[z] + (size_t)i0 * 8) = o;
}

struct GemmArgs {
  const void* A1[4]; const void* A2[4];
  const _Float16* W1[4]; const _Float16* W2[4];
  const float* b1[4];    const float* b2[4];
  void* out[4];
  float bscale[4];
  int K[4];
  int mode[4];
};

// epilogue shared by both GEMMs
template <int NMT>
__device__ static inline void gemm_epilogue(const GemmArgs& g, int z,
                                            v4f (&acc)[NMT][4], int m0, int n0,
                                            int wm, int wn, int quad, int l16) {
  const int mode = g.mode[z];
  #pragma unroll
  for (int nt = 0; nt < 4; ++nt) {
    const int col = n0 + wn + nt * 16 + l16;
    float bv = g.b1[z][col] * g.bscale[z];
    if (g.b2[z]) bv += g.b2[z][col];
    if (mode == 1) {
      // Vt[((b*12+h)*64+dk)*1024 + s'];  s = tile|q4|j -> s' = q4|tile|j
      _Float16* outp = (_Float16*)g.out[z];
      const int h = col >> 6, dk = col & 63;
      #pragma unroll
      for (int mt = 0; mt < NMT; ++mt) {
        const int row = m0 + wm + mt * 16 + quad * 4;
        const int b = row >> 10, s = row & 1023;
        const int sp = (s & ~31) | ((s & 12) << 1) | ((s & 16) >> 2);
        v4h pack = {(_Float16)(acc[mt][nt][0] + bv), (_Float16)(acc[mt][nt][1] + bv),
                    (_Float16)(acc[mt][nt][2] + bv), (_Float16)(acc[mt][nt][3] + bv)};
        *(v4h*)&outp[(size_t)((b * 12 + h) * 64 + dk) * 1024 + sp] = pack;
      }
    } else {
      #pragma unroll
      for (int mt = 0; mt < NMT; ++mt)
        #pragma unroll
        for (int r = 0; r < 4; ++r) {
          const int row = m0 + wm + mt * 16 + quad * 4 + r;
          const float v = acc[mt][nt][r] + bv;
          if (mode == 2) ((float*)g.out[z])[(size_t)row * 768 + col] = v;
          else ((_Float16*)g.out[z])[(size_t)row * 768 + col] = (_Float16)v;
        }
    }
  }
}

// ---------------- projection GEMM (fp32 A), counted-vmcnt pipeline ----------
// 128x128 tile, BK=64. A: fp32 HBM -> regs -> cvt f16 -> swizzled ds_write
// (single 16 KB buffer). W: f16 via global_load_lds, double-buffered (32 KB).
// 48 KB LDS -> 3 blocks/CU; grid 768 = 256*3 fully co-resident.
// Raw s_barrier + counted vmcnt: stageW(k) is drained by vmcnt(12) where the
// 12 = loadA(k+1)[8] + stageW(k+1)[4] just issued. Never vmcnt(0) mid-loop.
__global__ __launch_bounds__(256) void gemm_proj(GemmArgs g) {
  __shared__ _Float16 a_lds[128 * 64];
  __shared__ _Float16 w_lds[2 * 128 * 64];
  const int z = blockIdx.z;
  const int KK = g.K[z];
  const int tid = threadIdx.x;
  const int w = tid >> 6, lane = tid & 63, quad = lane >> 4, l16 = lane & 15;
  const int m0 = blockIdx.x * 128, n0 = blockIdx.y * 128;
  const int wm = (w >> 1) * 64, wn = (w & 1) * 64;

  size_t srcOffW[4]; int ldsOffW[4];
  #pragma unroll
  for (int i = 0; i < 4; ++i) {
    const int c = i * 256 + tid, row = c >> 3, slot = c & 7;
    srcOffW[i] = (size_t)row * 768 + (size_t)((slot ^ (row & 7)) * 8);
    ldsOffW[i] = (i * 256 + w * 64) * 8;
  }
  auto stageW = [&](const _Float16* Wsrc, int kc, int buf) {
    #pragma unroll
    for (int i = 0; i < 4; ++i)
      async_copy16(Wsrc + (size_t)n0 * 768 + kc + srcOffW[i],
                   &w_lds[buf * 8192 + ldsOffW[i]]);
  };

  int rowA[4], colA[4], dstA[4];
  float4 areg[4][2];
  #pragma unroll
  for (int i = 0; i < 4; ++i) {
    const int s = i * 256 + tid, row = s >> 3, slot = s & 7;
    rowA[i] = row;
    colA[i] = (slot ^ (row & 7)) * 8;
    dstA[i] = s * 8;
  }
  auto loadA = [&](const float* Af, int kc) {
    #pragma unroll
    for (int i = 0; i < 4; ++i) {
      const float* p = Af + (size_t)(m0 + rowA[i]) * 768 + kc + colA[i];
      areg[i][0] = *(const float4*)p;
      areg[i][1] = *(const float4*)(p + 4);
    }
  };
  auto writeA = [&]() {
    #pragma unroll
    for (int i = 0; i < 4; ++i) {
      const float4 f0 = areg[i][0], f1 = areg[i][1];
      v8h o = {(_Float16)f0.x, (_Float16)f0.y, (_Float16)f0.z, (_Float16)f0.w,
               (_Float16)f1.x, (_Float16)f1.y, (_Float16)f1.z, (_Float16)f1.w};
      *(v8h*)&a_lds[dstA[i]] = o;
    }
  };

  const void* A1 = g.A1[z]; const void* A2 = g.A2[z];
  const _Float16* W1 = g.W1[z]; const _Float16* W2 = g.W2[z];

  v4f acc[4][4] = {};

  // prologue: A(0) -> regs, W(0) -> wbuf0
  loadA((const float*)A1, 0);
  stageW(W1, 0, 0);

  for (int k0 = 0; k0 < KK; k0 += 64) {
    const int cur = (k0 >> 6) & 1;
    const int k0n = k0 + 64;
    const bool hn = k0n < KK;
    const int kcn = (k0n < 768) ? k0n : k0n - 768;
    const bool nf = k0n < 768;

    // regs -> a_lds (compiler inserts precise vmcnt for its own loads;
    // loadA below can't hoist above this: register WAR on areg)
    writeA();
    if (hn) {
      loadA((const float*)(nf ? A1 : A2), kcn);   // 8 dwordx4, younger
      stageW(nf ? W1 : W2, kcn, cur ^ 1);         // 4 lds-copies, younger
    }
    SCHED_FENCE();
    if (hn) asm volatile("s_waitcnt vmcnt(12) lgkmcnt(0)" ::: "memory");
    else    asm volatile("s_waitcnt vmcnt(0) lgkmcnt(0)" ::: "memory");
    SCHED_FENCE();
    __builtin_amdgcn_s_barrier();   // a_lds + wbuf[cur] ready everywhere
    SCHED_FENCE();

    const _Float16* wl = &w_lds[cur * 8192];
    #pragma unroll
    for (int kh = 0; kh < 2; ++kh) {
      v8h af[4], bf[4];
      #pragma unroll
      for (int mt = 0; mt < 4; ++mt) {
        const int r = wm + mt * 16 + l16;
        af[mt] = *(const v8h*)&a_lds[r * 64 + (((kh * 4 + quad) ^ (r & 7)) * 8)];
      }
      #pragma unroll
      for (int nt = 0; nt < 4; ++nt) {
        const int r = wn + nt * 16 + l16;
        bf[nt] = *(const v8h*)&wl[r * 64 + (((kh * 4 + quad) ^ (r & 7)) * 8)];
      }
      __builtin_amdgcn_s_setprio(1);
      #pragma unroll
      for (int mt = 0; mt < 4; ++mt)
        #pragma unroll
        for (int nt = 0; nt < 4; ++nt)
          acc[mt][nt] = MFMA_F16(af[mt], bf[nt], acc[mt][nt], 0, 0, 0);
      __builtin_amdgcn_s_setprio(0);
    }
    SCHED_FENCE();
    __builtin_amdgcn_s_barrier();   // readers done before next writeA
    SCHED_FENCE();
  }

  gemm_epilogue<4>(g, z, acc, m0, n0, wm, wn, quad, l16);
}

// ---------------- output GEMM (f16 A), 64x128 tile, dbuf staging ------------
__global__ __launch_bounds__(256) void gemm_out(GemmArgs g) {
  __shared__ _Float16 a_lds[2 * 64 * 64];
  __shared__ _Float16 w_lds[2 * 128 * 64];
  const int z = 0;
  const int KK = g.K[z];
  const int tid = threadIdx.x;
  const int w = tid >> 6, lane = tid & 63, quad = lane >> 4, l16 = lane & 15;
  const int m0 = blockIdx.x * 64, n0 = blockIdx.y * 128;
  const int wm = (w >> 1) * 32, wn = (w & 1) * 64;

  size_t srcOffW[4]; int ldsOffW[4];
  #pragma unroll
  for (int i = 0; i < 4; ++i) {
    const int c = i * 256 + tid, row = c >> 3, slot = c & 7;
    srcOffW[i] = (size_t)row * 768 + (size_t)((slot ^ (row & 7)) * 8);
    ldsOffW[i] = (i * 256 + w * 64) * 8;
  }
  const _Float16* A1 = (const _Float16*)g.A1[z];
  const _Float16* W1 = g.W1[z];

  auto stage = [&](int kc, int buf) {
    #pragma unroll
    for (int i = 0; i < 2; ++i)
      async_copy16(A1 + (size_t)m0 * 768 + kc + srcOffW[i],
                   &a_lds[buf * 4096 + ldsOffW[i]]);
    #pragma unroll
    for (int i = 0; i < 4; ++i)
      async_copy16(W1 + (size_t)n0 * 768 + kc + srcOffW[i],
                   &w_lds[buf * 8192 + ldsOffW[i]]);
  };

  v4f acc[2][4] = {};
  stage(0, 0);

  for (int k0 = 0; k0 < KK; k0 += 64) {
    const int cur = (k0 >> 6) & 1;
    const bool hn = k0 + 64 < KK;
    if (hn) stage(k0 + 64, cur ^ 1);
    SCHED_FENCE();
    if (hn) asm volatile("s_waitcnt vmcnt(6) lgkmcnt(0)" ::: "memory");
    else    asm volatile("s_waitcnt vmcnt(0) lgkmcnt(0)" ::: "memory");
    SCHED_FENCE();
    __builtin_amdgcn_s_barrier();
    SCHED_FENCE();

    const _Float16* al = &a_lds[cur * 4096];
    const _Float16* wl = &w_lds[cur * 8192];
    #pragma unroll
    for (int kh = 0; kh < 2; ++kh) {
      v8h af[2], bf[4];
      #pragma unroll
      for (int mt = 0; mt < 2; ++mt) {
        const int r = wm + mt * 16 + l16;
        af[mt] = *(const v8h*)&al[r * 64 + (((kh * 4 + quad) ^ (r & 7)) * 8)];
      }
      #pragma unroll
      for (int nt = 0; nt < 4; ++nt) {
        const int r = wn + nt * 16 + l16;
        bf[nt] = *(const v8h*)&wl[r * 64 + (((kh * 4 + quad) ^ (r & 7)) * 8)];
      }
      __builtin_amdgcn_s_setprio(1);
      #pragma unroll
      for (int mt = 0; mt < 2; ++mt)
        #pragma unroll
        for (int nt = 0; nt < 4; ++nt)
          acc[mt][nt] = MFMA_F16(af[mt], bf[nt], acc[mt][nt], 0, 0, 0);
      __builtin_amdgcn_s_setprio(0);
    }
    SCHED_FENCE();
    __builtin_amdgcn_s_barrier();   // staging for next iter may overwrite buf
    SCHED_FENCE();
  }

  gemm_epilogue<2>(g, z, acc, m0, n0, wm, wn, quad, l16);
}

// ---------------- fused dual-time attention (unchanged, verified) ----------
__global__ __launch_bounds__(256) void attn(
    const _Float16* __restrict__ Q,
    const _Float16* __restrict__ KT0, const _Float16* __restrict__ KT1,
    const _Float16* __restrict__ Vt,   // [48*64][1024] permuted
    _Float16* __restrict__ X)          // [B*S,768]
{
  __shared__ _Float16 lds[6 * 4096];

  const int tid = threadIdx.x;
  const int w = tid >> 6, lane = tid & 63, quad = lane >> 4, l16 = lane & 15;

  const int orig = blockIdx.y * 16 + blockIdx.x;
  const int wgid = (orig & 7) * 96 + (orig >> 3);
  const int bh = wgid >> 4, q0 = (wgid & 15) * 64;
  const int b = bh / 12, h = bh % 12;
  const size_t base = (size_t)b * 1024 * 768 + h * 64;

  const _Float16* k0s = KT0 + base;
  const _Float16* k1s = KT1 + base;
  const _Float16* vs  = Vt + (size_t)bh * 64 * 1024;

  size_t ktOff[2], vOff[2]; int ldsOff[2];
  #pragma unroll
  for (int i = 0; i < 2; ++i) {
    const int c = i * 256 + w * 64 + lane, row = c >> 3, slot = c & 7;
    const int logical = slot ^ (row & 7);
    ktOff[i] = (size_t)row * 768 + (size_t)(logical * 8);
    vOff[i] = (size_t)row * 1024 + (size_t)(logical * 8);
    ldsOff[i] = c * 8;
  }
  auto stage = [&](int buf) {
    #pragma unroll
    for (int i = 0; i < 2; ++i) {
      async_copy16(k0s + ktOff[i], &lds[buf * 4096 + ldsOff[i]]);
      async_copy16(k1s + ktOff[i], &lds[8192 + buf * 4096 + ldsOff[i]]);
      async_copy16(vs + vOff[i], &lds[16384 + buf * 4096 + ldsOff[i]]);
    }
    k0s += 64 * 768; k1s += 64 * 768; vs += 64;
  };

  const _Float16* Qw = Q + base + (size_t)(q0 + w * 16) * 768;
  const v8h qf0 = *(const v8h*)(Qw + (size_t)l16 * 768 + quad * 8);
  const v8h qf1 = *(const v8h*)(Qw + (size_t)l16 * 768 + 32 + quad * 8);

  int ra0[4], ra1[4];
  #pragma unroll
  for (int t = 0; t < 4; ++t) {
    const int r = t * 16 + l16, rw = r & 7;
    ra0[t] = (r * 64 + ((quad ^ rw) * 8)) * 2;
    ra1[t] = ra0[t] ^ 64;
  }

  const _Float16 one = (_Float16)1.f;
  const v8h ones8 = {one, one, one, one, one, one, one, one};
  v4f o[2][4] = {};      // O^T tiles [t][dkt]
  v4f osum[2] = {};      // softmax denominators

  auto body = [&](int B, bool doStage) {   // B = buf * 8192 (byte offset)
    __syncthreads();
    if (doStage) stage((B == 0) ? 1 : 0);

    const char* L = (const char*)lds;

    v4f s[2][4];
    __builtin_amdgcn_s_setprio(1);
    #pragma unroll
    for (int kvt = 0; kvt < 4; ++kvt) {
      const v8h k00 = *(const v8h*)(L + B + ra0[kvt]);
      const v8h k01 = *(const v8h*)(L + B + ra1[kvt]);
      const v8h k10 = *(const v8h*)(L + 16384 + B + ra0[kvt]);
      const v8h k11 = *(const v8h*)(L + 16384 + B + ra1[kvt]);
      s[0][kvt] = MFMA_F16(k00, qf0, v4f{}, 0, 0, 0);
      s[0][kvt] = MFMA_F16(k01, qf1, s[0][kvt], 0, 0, 0);
      s[1][kvt] = MFMA_F16(k10, qf0, v4f{}, 0, 0, 0);
      s[1][kvt] = MFMA_F16(k11, qf1, s[1][kvt], 0, 0, 0);
    }
    __builtin_amdgcn_s_setprio(0);

    v8h pb8[2][2];
    #pragma unroll
    for (int t = 0; t < 2; ++t)
      #pragma unroll
      for (int gg = 0; gg < 2; ++gg) {
        const v4f sa = s[t][gg * 2], sb = s[t][gg * 2 + 1];
        const v2h a0 = pkrtz(EXP2F(sa[0]), EXP2F(sa[1]));
        const v2h a1 = pkrtz(EXP2F(sa[2]), EXP2F(sa[3]));
        const v2h b0 = pkrtz(EXP2F(sb[0]), EXP2F(sb[1]));
        const v2h b1 = pkrtz(EXP2F(sb[2]), EXP2F(sb[3]));
        pb8[t][gg] = v8h{a0[0], a0[1], a1[0], a1[1], b0[0], b0[1], b1[0], b1[1]};
        osum[t] = MFMA_F16(ones8, pb8[t][gg], osum[t], 0, 0, 0);
      }

    __builtin_amdgcn_s_setprio(1);
    #pragma unroll
    for (int dkt = 0; dkt < 4; ++dkt) {
      const v8h v0 = *(const v8h*)(L + 32768 + B + ra0[dkt]);
      const v8h v1 = *(const v8h*)(L + 32768 + B + ra1[dkt]);
      o[0][dkt] = MFMA_F16(v0, pb8[0][0], o[0][dkt], 0, 0, 0);
      o[0][dkt] = MFMA_F16(v1, pb8[0][1], o[0][dkt], 0, 0, 0);
      o[1][dkt] = MFMA_F16(v0, pb8[1][0], o[1][dkt], 0, 0, 0);
      o[1][dkt] = MFMA_F16(v1, pb8[1][1], o[1][dkt], 0, 0, 0);
    }
    __builtin_amdgcn_s_setprio(0);
  };

  stage(0);
  for (int it = 0; it < 7; ++it) {
    body(0, true);
    body(8192, true);
  }
  body(0, true);
  body(8192, false);

  const float i0 = 1.0f / osum[0][0], i1 = 1.0f / osum[1][0];

  _Float16* Xw = X + base + (size_t)(q0 + w * 16 + l16) * 768;
  #pragma unroll
  for (int dkt = 0; dkt < 4; ++dkt) {
    v4h pack;
    #pragma unroll
    for (int r = 0; r < 4; ++r)
      pack[r] = (_Float16)(o[0][dkt][r] * i0 + o[1][dkt][r] * i1);
    *(v4h*)&Xw[dkt * 16 + quad * 4] = pack;
  }
}

extern "C" void kernel_launch(void* const* d_in, const int* in_sizes, int n_in,
                              void* d_out, int out_size, void* d_ws, size_t ws_size,
                              hipStream_t stream) {
  const float* query = (const float*)d_in[0];
  const float* key   = (const float*)d_in[1];
  const float* value = (const float*)d_in[2];
  const float* times = (const float*)d_in[3];
  const float* Wq = (const float*)d_in[4];  const float* bq = (const float*)d_in[5];
  const float* Wk = (const float*)d_in[6];  const float* bk = (const float*)d_in[7];
  const float* Wv = (const float*)d_in[8];  const float* bv = (const float*)d_in[9];
  const float* Wt = (const float*)d_in[10]; const float* bt = (const float*)d_in[11];
  const float* Wo = (const float*)d_in[12]; const float* bo = (const float*)d_in[13];
  float* out = (float*)d_out;

  const size_t NELEM = (size_t)4096 * 768;
  const size_t WELEM = (size_t)768 * 768;
  const float QSCALE = 0.125f * 1.4426950408889634f;  // 1/sqrt(64)*log2(e)

  char* ws = (char*)d_ws;
  size_t off = 0;
  auto alloc = [&](size_t bytes) {
    void* p = ws + off; off += (bytes + 255) & ~(size_t)255; return p;
  };
  _Float16* wqh = (_Float16*)alloc(WELEM * 2);
  _Float16* wkh = (_Float16*)alloc(WELEM * 2);
  _Float16* wvh = (_Float16*)alloc(WELEM * 2);
  _Float16* wth = (_Float16*)alloc(WELEM * 2);
  _Float16* woh = (_Float16*)alloc(WELEM * 2);
  _Float16* Qh  = (_Float16*)alloc(NELEM * 2);
  _Float16* KT0 = (_Float16*)alloc(NELEM * 2);
  _Float16* KT1 = (_Float16*)alloc(NELEM * 2);
  _Float16* Vt  = (_Float16*)alloc(NELEM * 2);
  _Float16* Xh  = (_Float16*)alloc(NELEM * 2);

  // ---- 1. weight cast ----
  CastArgs ca = {};
  const int nW8 = (int)(WELEM / 8);
  const float* csrc[5] = {Wq, Wk, Wv, Wt, Wo};
  _Float16* cdst[5] = {wqh, wkh, wvh, wth, woh};
  int acc8 = 0;
  for (int i = 0; i < 5; ++i) {
    ca.src[i] = csrc[i]; ca.dst[i] = cdst[i];
    ca.start[i] = acc8;
    acc8 += nW8;
    ca.scale[i] = (i == 0) ? QSCALE : 1.0f;
  }
  ca.start[5] = acc8;
  cast_all<<<dim3((acc8 + 255) / 256), 256, 0, stream>>>(ca);

  // ---- 2. batched projections: z = {KT0, KT1, Q, V}, fp32 A inputs ----
  GemmArgs pa = {};
  pa.A1[0] = times;         pa.A2[0] = key; pa.W1[0] = wth; pa.W2[0] = wkh;
  pa.b1[0] = bt; pa.b2[0] = bk; pa.out[0] = KT0; pa.bscale[0] = 1.0f;
  pa.K[0] = 1536; pa.mode[0] = 0;
  pa.A1[1] = times + NELEM; pa.A2[1] = key; pa.W1[1] = wth; pa.W2[1] = wkh;
  pa.b1[1] = bt; pa.b2[1] = bk; pa.out[1] = KT1; pa.bscale[1] = 1.0f;
  pa.K[1] = 1536; pa.mode[1] = 0;
  pa.A1[2] = query; pa.A2[2] = query; pa.W1[2] = wqh; pa.W2[2] = wqh;
  pa.b1[2] = bq; pa.b2[2] = nullptr; pa.out[2] = Qh; pa.bscale[2] = QSCALE;
  pa.K[2] = 768; pa.mode[2] = 0;
  pa.A1[3] = value; pa.A2[3] = value; pa.W1[3] = wvh; pa.W2[3] = wvh;
  pa.b1[3] = bv; pa.b2[3] = nullptr; pa.out[3] = Vt; pa.bscale[3] = 1.0f;
  pa.K[3] = 768; pa.mode[3] = 1;
  gemm_proj<<<dim3(32, 6, 4), 256, 0, stream>>>(pa);

  // ---- 3. fused dual-time attention -> Xh ----
  attn<<<dim3(16, 48), 256, 0, stream>>>(Qh, KT0, KT1, Vt, Xh);

  // ---- 4. output projection -> d_out (fp32) ----
  GemmArgs oa = {};
  oa.A1[0] = Xh; oa.A2[0] = Xh; oa.W1[0] = woh; oa.W2[0] = woh;
  oa.b1[0] = bo; oa.b2[0] = nullptr; oa.out[0] = out; oa.bscale[0] = 1.0f;
  oa.K[0] = 768; oa.mode[0] = 2;
  gemm_out<<<dim3(64, 6, 1), 256, 0, stream>>>(oa);
}